// Round 13
// baseline (210.442 us; speedup 1.0000x reference)
//
#include <hip/hip_runtime.h>
#include <hip/hip_bf16.h>

#define N_NODES 50000
#define N_EDGES 800000
#define EMB 100
#define HALF_EMB 50
#define QEMB 25
#define NORM_EPS 1e-12f
#define BROWS 128                      // rows per bucket
#define NB ((N_NODES + BROWS - 1) / BROWS)   // 391 buckets
#define CAP 4096                       // slab capacity per bucket (avg fill ~2046)
#define EPB 4096                       // edges per partition block -> run len ~10.5
#define SCAT_BLOCKS ((N_EDGES + EPB - 1) / EPB)   // 196
#define CONV_BLOCKS 3125               // 16 waves x 3125 = 50000 nodes exactly

// Dispatch A (merged): blocks [0,196) = bucket scatter (1024 thr); blocks
// [196, 196+3125) = conv_emb. Disjoint inputs -> conv fills idle CUs.
__global__ __launch_bounds__(1024) void scatter_conv(
        const int* __restrict__ adj_row, const int* __restrict__ adj_col,
        const float* __restrict__ adj_val, int* __restrict__ bucket_cnt,
        int2* __restrict__ slab,
        const float* __restrict__ emb, float* __restrict__ norm0,
        __hip_bfloat162* __restrict__ xb) {
    const int t = threadIdx.x;
    if (blockIdx.x >= SCAT_BLOCKS) {
        // ---- conv_emb: one wave per node ----
        int wave = (blockIdx.x - SCAT_BLOCKS) * 16 + (t >> 6);
        int lane = t & 63;
        if (wave >= N_NODES) return;
        float2 v = make_float2(0.0f, 0.0f);
        size_t idx = (size_t)wave * HALF_EMB + lane;
        if (lane < HALF_EMB) v = ((const float2*)emb)[idx];
        float s = v.x * v.x + v.y * v.y;
        #pragma unroll
        for (int off = 32; off > 0; off >>= 1) s += __shfl_xor(s, off);
        if (lane == 0) norm0[wave] = sqrtf(s);
        if (lane < HALF_EMB) {
            __hip_bfloat162 b;
            b.x = __float2bfloat16(v.x);
            b.y = __float2bfloat16(v.y);
            xb[idx] = b;
        }
        return;
    }
    // ---- bucket scatter ----
    __shared__ int hist[NB];
    __shared__ int cur[NB];
    const int base_e = blockIdx.x * EPB;
    for (int i = t; i < NB; i += 1024) hist[i] = 0;
    __syncthreads();
    int rows[EPB / 1024];
    #pragma unroll
    for (int j = 0; j < EPB / 1024; ++j) {
        int e = base_e + j * 1024 + t;
        int r = (e < N_EDGES) ? adj_row[e] : -1;
        rows[j] = r;
        if (r >= 0) atomicAdd(&hist[r >> 7], 1);
    }
    __syncthreads();
    for (int i = t; i < NB; i += 1024) {
        int c = hist[i];
        cur[i] = (c > 0) ? atomicAdd(&bucket_cnt[i], c) : 0;
    }
    __syncthreads();
    #pragma unroll
    for (int j = 0; j < EPB / 1024; ++j) {
        int e = base_e + j * 1024 + t;
        int r = rows[j];
        if (r >= 0) {
            int b = r >> 7;
            int p = atomicAdd(&cur[b], 1);
            unsigned rc = ((unsigned)r << 16) | (unsigned)adj_col[e];
            slab[(size_t)b * CAP + p] = make_int2((int)rc, __float_as_int(adj_val[e]));
        }
    }
}

// Dispatch B: per-bucket counting sort (1024 thr) -> compressed CSR + row_ptr.
__global__ __launch_bounds__(1024) void csr_build(
        const int* __restrict__ bucket_cnt, const int2* __restrict__ slab,
        unsigned* __restrict__ csr4, int* __restrict__ row_ptr) {
    __shared__ int2 eds[CAP];
    __shared__ int hist[BROWS];   // later reused as scatter cursor
    __shared__ int incl[BROWS];
    __shared__ int red[1024];
    const int b = blockIdx.x, t = threadIdx.x;
    // embedded exclusive prefix: base = sum_{i<b} cnt[i]  (b < 391 < 1024)
    red[t] = (t < b) ? bucket_cnt[t] : 0;
    __syncthreads();
    #pragma unroll
    for (int off = 512; off > 0; off >>= 1) {
        if (t < off) red[t] += red[t + off];
        __syncthreads();
    }
    const int base = red[0];
    const int cnt = bucket_cnt[b];
    for (int i = t; i < cnt; i += 1024) eds[i] = slab[(size_t)b * CAP + i];
    if (t < BROWS) hist[t] = 0;
    __syncthreads();
    for (int i = t; i < cnt; i += 1024)
        atomicAdd(&hist[(int)(((unsigned)eds[i].x) >> 16) & (BROWS - 1)], 1);
    __syncthreads();
    int v = (t < BROWS) ? hist[t] : 0;
    if (t < BROWS) incl[t] = v;
    __syncthreads();
    #pragma unroll
    for (int off = 1; off < BROWS; off <<= 1) {
        int n = (t >= off && t < BROWS) ? incl[t - off] : 0;
        __syncthreads();
        if (t < BROWS) incl[t] += n;
        __syncthreads();
    }
    int ex = (t < BROWS) ? (incl[t] - v) : 0;
    __syncthreads();
    if (t < BROWS) hist[t] = ex;          // cursor init
    int gr = b * BROWS + t;
    if (t < BROWS && gr < N_NODES) row_ptr[gr] = base + ex;
    if (b == 0 && t == 0) row_ptr[N_NODES] = N_EDGES;
    __syncthreads();
    for (int i = t; i < cnt; i += 1024) {
        int2 e = eds[i];
        int l = (int)(((unsigned)e.x) >> 16) & (BROWS - 1);
        int p = atomicAdd(&hist[l], 1);
        unsigned col = (unsigned)e.x & 0xFFFFu;
        __hip_bfloat16 hv = __float2bfloat16(__int_as_float(e.y));
        unsigned vb = (unsigned)*reinterpret_cast<unsigned short*>(&hv);
        csr4[base + p] = (col << 16) | vb;
    }
}

// unpack 4 bf16 (uint2) -> float4, bit-twiddle only
__device__ inline float4 up4(uint2 u) {
    float4 f;
    f.x = __uint_as_float(u.x << 16);
    f.y = __uint_as_float(u.x & 0xFFFF0000u);
    f.z = __uint_as_float(u.y << 16);
    f.w = __uint_as_float(u.y & 0xFFFF0000u);
    return f;
}

// SpMM with SCALAR (wave-uniform) edge-record loads: start/deg are identical
// across the wave, so csr4[su+d] compiles to s_load on the SMEM pipe — no
// lane-load, no shfl/ds_bpermute, no lgkmcnt in the gather address path.
// Half-wave h=lane>>5 owns the odd/even edge of each pair; lane (h,c<25)
// gathers uint2 = 4 bf16 features. Main loop: 16 edges / 8 outstanding gathers.
// rec = col<<16 | bf16(val): col = rec>>16, val = bits(rec<<16) (exact).
__global__ void spmm_fused(const int* __restrict__ row_ptr,
                           const unsigned* __restrict__ csr4,
                           const uint2* __restrict__ xb,
                           uint2* __restrict__ yb,
                           float* __restrict__ norm_out,
                           const float* __restrict__ a,
                           const uint2* __restrict__ ep0,
                           const uint2* __restrict__ ep1,
                           const float* __restrict__ norms,
                           float* __restrict__ out,
                           int final_layer) {
    int wave = blockIdx.x * (blockDim.x >> 6) + (threadIdx.x >> 6);
    int lane = threadIdx.x & 63;
    if (wave >= N_NODES) return;
    int su   = __builtin_amdgcn_readfirstlane(row_ptr[wave]);
    int degu = __builtin_amdgcn_readfirstlane(row_ptr[wave + 1]) - su;
    int h = lane >> 5, c = lane & 31;
    bool act = (c < QEMB);
    float4 acc = make_float4(0.0f, 0.0f, 0.0f, 0.0f);
    int d = 0;
    for (; d + 16 <= degu; d += 16) {   // 8 gathers : 16 edges
        unsigned r0 = csr4[su + d + 0],  r1 = csr4[su + d + 1];
        unsigned r2 = csr4[su + d + 2],  r3 = csr4[su + d + 3];
        unsigned r4 = csr4[su + d + 4],  r5 = csr4[su + d + 5];
        unsigned r6 = csr4[su + d + 6],  r7 = csr4[su + d + 7];
        unsigned r8 = csr4[su + d + 8],  r9 = csr4[su + d + 9];
        unsigned rA = csr4[su + d + 10], rB = csr4[su + d + 11];
        unsigned rC = csr4[su + d + 12], rD = csr4[su + d + 13];
        unsigned rE = csr4[su + d + 14], rF = csr4[su + d + 15];
        unsigned e0 = h ? r1 : r0, e1 = h ? r3 : r2;
        unsigned e2 = h ? r5 : r4, e3 = h ? r7 : r6;
        unsigned e4 = h ? r9 : r8, e5 = h ? rB : rA;
        unsigned e6 = h ? rD : rC, e7 = h ? rF : rE;
        if (act) {
            uint2 u0 = xb[(size_t)(e0 >> 16) * QEMB + c];
            uint2 u1 = xb[(size_t)(e1 >> 16) * QEMB + c];
            uint2 u2 = xb[(size_t)(e2 >> 16) * QEMB + c];
            uint2 u3 = xb[(size_t)(e3 >> 16) * QEMB + c];
            uint2 u4 = xb[(size_t)(e4 >> 16) * QEMB + c];
            uint2 u5 = xb[(size_t)(e5 >> 16) * QEMB + c];
            uint2 u6 = xb[(size_t)(e6 >> 16) * QEMB + c];
            uint2 u7 = xb[(size_t)(e7 >> 16) * QEMB + c];
            float v0 = __uint_as_float(e0 << 16), v1 = __uint_as_float(e1 << 16);
            float v2 = __uint_as_float(e2 << 16), v3 = __uint_as_float(e3 << 16);
            float v4 = __uint_as_float(e4 << 16), v5 = __uint_as_float(e5 << 16);
            float v6 = __uint_as_float(e6 << 16), v7 = __uint_as_float(e7 << 16);
            float4 f;
            f = up4(u0); acc.x += v0*f.x; acc.y += v0*f.y; acc.z += v0*f.z; acc.w += v0*f.w;
            f = up4(u1); acc.x += v1*f.x; acc.y += v1*f.y; acc.z += v1*f.z; acc.w += v1*f.w;
            f = up4(u2); acc.x += v2*f.x; acc.y += v2*f.y; acc.z += v2*f.z; acc.w += v2*f.w;
            f = up4(u3); acc.x += v3*f.x; acc.y += v3*f.y; acc.z += v3*f.z; acc.w += v3*f.w;
            f = up4(u4); acc.x += v4*f.x; acc.y += v4*f.y; acc.z += v4*f.z; acc.w += v4*f.w;
            f = up4(u5); acc.x += v5*f.x; acc.y += v5*f.y; acc.z += v5*f.z; acc.w += v5*f.w;
            f = up4(u6); acc.x += v6*f.x; acc.y += v6*f.y; acc.z += v6*f.z; acc.w += v6*f.w;
            f = up4(u7); acc.x += v7*f.x; acc.y += v7*f.y; acc.z += v7*f.z; acc.w += v7*f.w;
        }
    }
    for (; d < degu; d += 2) {          // pair tail (wave-uniform guard)
        unsigned rA = csr4[su + d];
        unsigned rB = (d + 1 < degu) ? csr4[su + d + 1] : 0u;
        unsigned e = h ? rB : rA;
        if (act) {
            uint2 u = xb[(size_t)(e >> 16) * QEMB + c];
            float v = __uint_as_float(e << 16);
            float4 f = up4(u);
            acc.x += v * f.x; acc.y += v * f.y; acc.z += v * f.z; acc.w += v * f.w;
        }
    }
    // combine halves: both halves end with full row sums
    acc.x += __shfl_xor(acc.x, 32);
    acc.y += __shfl_xor(acc.y, 32);
    acc.z += __shfl_xor(acc.z, 32);
    acc.w += __shfl_xor(acc.w, 32);
    float s = 0.0f;
    if (h == 0 && act)
        s = acc.x * acc.x + acc.y * acc.y + acc.z * acc.z + acc.w * acc.w;
    #pragma unroll
    for (int off = 32; off > 0; off >>= 1) s += __shfl_xor(s, off);
    if (!final_layer) {
        if (h == 0 && act) {
            __hip_bfloat16 b0 = __float2bfloat16(acc.x);
            __hip_bfloat16 b1 = __float2bfloat16(acc.y);
            __hip_bfloat16 b2 = __float2bfloat16(acc.z);
            __hip_bfloat16 b3 = __float2bfloat16(acc.w);
            uint2 o;
            o.x = (unsigned)*(unsigned short*)&b0 | ((unsigned)*(unsigned short*)&b1 << 16);
            o.y = (unsigned)*(unsigned short*)&b2 | ((unsigned)*(unsigned short*)&b3 << 16);
            yb[(size_t)wave * QEMB + c] = o;
        }
        if (lane == 0) norm_out[wave] = sqrtf(s);
    } else {
        float s0 = a[0] / fmaxf(norms[wave], NORM_EPS);
        float s1 = a[1] / fmaxf(norms[N_NODES + wave], NORM_EPS);
        float s2 = a[2] / fmaxf(norms[2 * N_NODES + wave], NORM_EPS);
        float s3 = a[3] / fmaxf(sqrtf(s), NORM_EPS);
        if (h == 0 && act) {
            size_t idx = (size_t)wave * QEMB + c;
            float4 f0 = up4(ep0[idx]);   // bf16(emb)
            float4 f1 = up4(ep1[idx]);   // x1
            float4 f2 = up4(xb[idx]);    // x2 (the gather table, L2-warm)
            float4 o;
            o.x = s0 * f0.x + s1 * f1.x + s2 * f2.x + s3 * acc.x;
            o.y = s0 * f0.y + s1 * f1.y + s2 * f2.y + s3 * acc.y;
            o.z = s0 * f0.z + s1 * f1.z + s2 * f2.z + s3 * acc.z;
            o.w = s0 * f0.w + s1 * f1.w + s2 * f2.w + s3 * acc.w;
            ((float4*)out)[idx] = o;
        }
    }
}

extern "C" void kernel_launch(void* const* d_in, const int* in_sizes, int n_in,
                              void* d_out, int out_size, void* d_ws, size_t ws_size,
                              hipStream_t stream) {
    const int*   adj_row   = (const int*)d_in[0];
    const int*   adj_col   = (const int*)d_in[1];
    const float* adj_val   = (const float*)d_in[2];
    const float* embedding = (const float*)d_in[3];
    const float* a         = (const float*)d_in[4];
    float* out = (float*)d_out;

    // workspace layout. xb2 overlays slab (slab dead after csr_build,
    // xb2 first written in layer-2 spmm — stream-ordered, safe).
    int2* slab     = (int2*)d_ws;                                  // 12.8 MB
    unsigned* csr4 = (unsigned*)(slab + (size_t)NB * CAP);         // 3.2 MB
    uint2* xbE = (uint2*)(csr4 + N_EDGES);                         // 10 MB
    uint2* xb1 = xbE + (size_t)N_NODES * QEMB;                     // 10 MB
    float* norms = (float*)(xb1 + (size_t)N_NODES * QEMB);         // 3*50,000
    int* row_ptr    = (int*)(norms + 3 * N_NODES);                 // 50,001
    int* bucket_cnt = row_ptr + (N_NODES + 1);                     // NB
    uint2* xb2 = (uint2*)slab;                                     // overlay

    const int node_blocks = (N_NODES + 3) / 4;          // 4 waves / block

    // ---- CSR build: (scatter || emb prep) -> per-bucket sort ----
    hipMemsetAsync(bucket_cnt, 0, sizeof(int) * NB, stream);
    scatter_conv<<<SCAT_BLOCKS + CONV_BLOCKS, 1024, 0, stream>>>(
        adj_row, adj_col, adj_val, bucket_cnt, slab,
        embedding, norms, (__hip_bfloat162*)xbE);
    csr_build<<<NB, 1024, 0, stream>>>(bucket_cnt, slab, csr4, row_ptr);

    // ---- layer 1, 2 (raw bf16 + norm), layer 3 (fused epilogue) ----
    spmm_fused<<<node_blocks, 256, 0, stream>>>(row_ptr, csr4, xbE,
                                                xb1, norms + N_NODES, a,
                                                nullptr, nullptr, nullptr,
                                                nullptr, 0);
    spmm_fused<<<node_blocks, 256, 0, stream>>>(row_ptr, csr4, xb1,
                                                xb2, norms + 2 * N_NODES, a,
                                                nullptr, nullptr, nullptr,
                                                nullptr, 0);
    spmm_fused<<<node_blocks, 256, 0, stream>>>(row_ptr, csr4, xb2,
                                                nullptr, nullptr, a,
                                                xbE, xb1, norms,
                                                out, 1);
}